// Round 3
// baseline (1006.634 us; speedup 1.0000x reference)
//
#include <hip/hip_runtime.h>

// Problem constants
#define BB   512
#define CC   22
#define TT   1000
#define HH   64
#define NCLS 4
#define TC   250          // time chunk staged in LDS
#define NCHUNK (TT / TC)
#define XROW 12           // h2 slots per xs row (11 used, 48B rows: 0 conflicts in R4)

typedef _Float16 f16;
typedef __attribute__((ext_vector_type(2))) _Float16 h2;

// fast activations: v_exp + v_rcp (1 ulp) — absmax unchanged vs IEEE div (R6).
__device__ __forceinline__ float sigm(float x) {
    float e = __expf(-x);
    return __builtin_amdgcn_rcpf(1.0f + e);
}
__device__ __forceinline__ float tanh_(float x) {
    float e = __expf(-2.0f * fabsf(x));   // (0,1], no overflow
    float r = (1.0f - e) * __builtin_amdgcn_rcpf(1.0f + e);
    return copysignf(r, x);
}

__device__ __forceinline__ h2 u2h(unsigned u) {
    union { unsigned u; h2 h; } c; c.u = u; return c.h;
}
__device__ __forceinline__ unsigned h2u(h2 h) {
    union { unsigned u; h2 h; } c; c.h = h; return c.u;
}

// R7: TWO ROWS PER WAVE, zero barriers.
// R5/R6 post-mortem: per-step time ~1600 cyc in BOTH 1-wave (172 fdot2) and
// 2-wave-split (88 fdot2 + barrier) layouts -> the step is exposed-LATENCY
// bound, not issue bound, and with <=1 wave/SIMD there is nothing to hide it.
// TLP is structurally capped (512 rows < 1024 SIMDs), so the fix is ILP:
// one wave interleaves two independent rows. Row B's fdot2 issue fills row
// A's stalls (h LDS round-trip, W_fc load, trans chains, weight re-access)
// and vice versa. Weights are SHARED between the rows (no extra regs);
// W_fc loads are row-independent (loaded once per step, used by both rows).
// Single wave per block -> own-wave LDS only -> no __syncthreads anywhere.
__global__ __launch_bounds__(64, 1) void lstm_2row(
    const float* __restrict__ x,     // [B, C, T]
    const float* __restrict__ W_ih,  // [4H, C]
    const float* __restrict__ W_hh,  // [4H, H]
    const float* __restrict__ b_ih,  // [4H]
    const float* __restrict__ b_hh,  // [4H]
    const float* __restrict__ W_fc,  // [NCLS, T*H]
    const float* __restrict__ b_fc,  // [NCLS]
    float* __restrict__ out)         // [B, NCLS]
{
    __shared__ __align__(16) h2  xsA[TC][XROW];   // 12 KB: row A x chunk
    __shared__ __align__(16) h2  xsB[TC][XROW];   // 12 KB: row B x chunk
    __shared__ __align__(16) f16 hbA[HH];         // 128 B
    __shared__ __align__(16) f16 hbB[HH];         // 128 B

    const int lane = threadIdx.x;    // hidden unit
    const int rA   = blockIdx.x * 2;
    const int rB   = rA + 1;

    // ---- per-lane weights into registers (one-time), then pin ----
    unsigned whh[4][32];      // W_hh rows (f16 pairs) for gates i,f,g,o: 128 VGPR
    unsigned wih[4][11];      // W_ih rows: 44 VGPR
    float bias[4];
    #pragma unroll
    for (int g = 0; g < 4; ++g) {
        const int row = g * HH + lane;
        const float* wr = W_hh + row * HH;
        #pragma unroll
        for (int k = 0; k < 32; ++k)
            whh[g][k] = h2u(h2{(f16)wr[2 * k], (f16)wr[2 * k + 1]});
        const float* wi = W_ih + row * CC;
        #pragma unroll
        for (int k = 0; k < 11; ++k)
            wih[g][k] = h2u(h2{(f16)wi[2 * k], (f16)wi[2 * k + 1]});
        bias[g] = b_ih[row] + b_hh[row];
    }
    #pragma unroll
    for (int g = 0; g < 4; ++g) {
        #pragma unroll
        for (int k = 0; k < 32; ++k) asm volatile("" : "+v"(whh[g][k]));
        #pragma unroll
        for (int k = 0; k < 11; ++k) asm volatile("" : "+v"(wih[g][k]));
        asm volatile("" : "+v"(bias[g]));
    }

    hbA[lane] = (f16)0.0f;           // own-wave ordering; no barrier needed
    hbB[lane] = (f16)0.0f;
    float cA = 0.0f, cB = 0.0f;
    float fa0 = 0.f, fa1 = 0.f, fa2 = 0.f, fa3 = 0.f;   // FC acc row A
    float fb0 = 0.f, fb1 = 0.f, fb2 = 0.f, fb3 = 0.f;   // FC acc row B
    const float* p0 = W_fc + 0 * (TT * HH) + lane;
    const float* p1 = W_fc + 1 * (TT * HH) + lane;
    const float* p2 = W_fc + 2 * (TT * HH) + lane;
    const float* p3 = W_fc + 3 * (TT * HH) + lane;
    const float* xrowA = x + (size_t)rA * (CC * TT);
    const float* xrowB = x + (size_t)rB * (CC * TT);

    for (int chunk = 0; chunk < NCHUNK; ++chunk) {
        // ---- stage both rows' x chunks into LDS (own wave, no barrier) ----
        for (int tb = 0; tb < TC; tb += 64) {
            const int t = tb + lane;
            if (t < TC) {
                const float* gA = xrowA + chunk * TC + t;   // stride TT per channel
                const float* gB = xrowB + chunk * TC + t;
                union { h2 h[XROW]; uint4 q[3]; } UA, UB;
                #pragma unroll
                for (int k = 0; k < 11; ++k) {
                    UA.h[k] = h2{(f16)gA[(2 * k) * TT], (f16)gA[(2 * k + 1) * TT]};
                    UB.h[k] = h2{(f16)gB[(2 * k) * TT], (f16)gB[(2 * k + 1) * TT]};
                }
                UA.h[11] = h2{(f16)0.0f, (f16)0.0f};
                UB.h[11] = h2{(f16)0.0f, (f16)0.0f};
                uint4* dA = (uint4*)&xsA[t][0];
                uint4* dB = (uint4*)&xsB[t][0];
                dA[0] = UA.q[0]; dA[1] = UA.q[1]; dA[2] = UA.q[2];
                dB[0] = UB.q[0]; dB[1] = UB.q[1]; dB[2] = UB.q[2];
            }
        }
        // no __syncthreads: xs is own-wave data, DS ops in-order per wave

        for (int tt = 0; tt < TC; ++tt) {
            // W_fc loads (shared by both rows), issued first to drain early
            float w0 = *p0, w1 = *p1, w2 = *p2, w3 = *p3;
            p0 += HH; p1 += HH; p2 += HH; p3 += HH;

            // h broadcasts for both rows (same-address b128 reads)
            union { uint4 q[8]; h2 h[32]; } HA, HB;
            const uint4* ha = (const uint4*)hbA;
            const uint4* hb = (const uint4*)hbB;
            #pragma unroll
            for (int i = 0; i < 8; ++i) { HA.q[i] = ha[i]; HB.q[i] = hb[i]; }

            // x broadcasts for both rows
            union { uint4 q[3]; h2 h[XROW]; } XA, XB;
            const uint4* xa = (const uint4*)&xsA[tt][0];
            const uint4* xb = (const uint4*)&xsB[tt][0];
            XA.q[0] = xa[0]; XA.q[1] = xa[1]; XA.q[2] = xa[2];
            XB.q[0] = xb[0]; XB.q[1] = xb[1]; XB.q[2] = xb[2];

            // interleaved gate dots: 8 independent accumulator chains
            float aA0 = bias[0], aA1 = bias[1], aA2 = bias[2], aA3 = bias[3];
            float aB0 = bias[0], aB1 = bias[1], aB2 = bias[2], aB3 = bias[3];
            #pragma unroll
            for (int k = 0; k < 11; ++k) {
                aA0 = __builtin_amdgcn_fdot2(XA.h[k], u2h(wih[0][k]), aA0, false);
                aB0 = __builtin_amdgcn_fdot2(XB.h[k], u2h(wih[0][k]), aB0, false);
                aA1 = __builtin_amdgcn_fdot2(XA.h[k], u2h(wih[1][k]), aA1, false);
                aB1 = __builtin_amdgcn_fdot2(XB.h[k], u2h(wih[1][k]), aB1, false);
                aA2 = __builtin_amdgcn_fdot2(XA.h[k], u2h(wih[2][k]), aA2, false);
                aB2 = __builtin_amdgcn_fdot2(XB.h[k], u2h(wih[2][k]), aB2, false);
                aA3 = __builtin_amdgcn_fdot2(XA.h[k], u2h(wih[3][k]), aA3, false);
                aB3 = __builtin_amdgcn_fdot2(XB.h[k], u2h(wih[3][k]), aB3, false);
            }
            #pragma unroll
            for (int k = 0; k < 32; ++k) {
                aA0 = __builtin_amdgcn_fdot2(HA.h[k], u2h(whh[0][k]), aA0, false);
                aB0 = __builtin_amdgcn_fdot2(HB.h[k], u2h(whh[0][k]), aB0, false);
                aA1 = __builtin_amdgcn_fdot2(HA.h[k], u2h(whh[1][k]), aA1, false);
                aB1 = __builtin_amdgcn_fdot2(HB.h[k], u2h(whh[1][k]), aB1, false);
                aA2 = __builtin_amdgcn_fdot2(HA.h[k], u2h(whh[2][k]), aA2, false);
                aB2 = __builtin_amdgcn_fdot2(HB.h[k], u2h(whh[2][k]), aB2, false);
                aA3 = __builtin_amdgcn_fdot2(HA.h[k], u2h(whh[3][k]), aA3, false);
                aB3 = __builtin_amdgcn_fdot2(HB.h[k], u2h(whh[3][k]), aB3, false);
            }

            // lane-local LSTM updates (independent chains, compiler interleaves)
            float iA = sigm(aA0), fA = sigm(aA1), gA = tanh_(aA2), oA = sigm(aA3);
            float iB = sigm(aB0), fB = sigm(aB1), gB = tanh_(aB2), oB = sigm(aB3);
            cA = fA * cA + iA * gA;
            cB = fB * cB + iB * gB;
            float hA = oA * tanh_(cA);
            float hB = oB * tanh_(cB);

            // fused FC accumulation (shared W_fc values)
            fa0 += hA * w0; fa1 += hA * w1; fa2 += hA * w2; fa3 += hA * w3;
            fb0 += hB * w0; fb1 += hB * w1; fb2 += hB * w2; fb3 += hB * w3;

            // publish h for next step (own-wave LDS, in-order DS pipe)
            hbA[lane] = (f16)hA;
            hbB[lane] = (f16)hB;
        }
    }

    // ---- FC reduce over hid (wave shuffle) + softmax, both rows ----
    #pragma unroll
    for (int off = 32; off; off >>= 1) {
        fa0 += __shfl_down(fa0, off); fa1 += __shfl_down(fa1, off);
        fa2 += __shfl_down(fa2, off); fa3 += __shfl_down(fa3, off);
        fb0 += __shfl_down(fb0, off); fb1 += __shfl_down(fb1, off);
        fb2 += __shfl_down(fb2, off); fb3 += __shfl_down(fb3, off);
    }
    if (lane == 0) {
        {
            float l0 = fa0 + b_fc[0], l1 = fa1 + b_fc[1];
            float l2 = fa2 + b_fc[2], l3 = fa3 + b_fc[3];
            float m  = fmaxf(fmaxf(l0, l1), fmaxf(l2, l3));
            float e0 = __expf(l0 - m), e1 = __expf(l1 - m);
            float e2 = __expf(l2 - m), e3 = __expf(l3 - m);
            float is = __builtin_amdgcn_rcpf(e0 + e1 + e2 + e3);
            float4 o; o.x = e0 * is; o.y = e1 * is; o.z = e2 * is; o.w = e3 * is;
            *(float4*)(out + rA * NCLS) = o;
        }
        {
            float l0 = fb0 + b_fc[0], l1 = fb1 + b_fc[1];
            float l2 = fb2 + b_fc[2], l3 = fb3 + b_fc[3];
            float m  = fmaxf(fmaxf(l0, l1), fmaxf(l2, l3));
            float e0 = __expf(l0 - m), e1 = __expf(l1 - m);
            float e2 = __expf(l2 - m), e3 = __expf(l3 - m);
            float is = __builtin_amdgcn_rcpf(e0 + e1 + e2 + e3);
            float4 o; o.x = e0 * is; o.y = e1 * is; o.z = e2 * is; o.w = e3 * is;
            *(float4*)(out + rB * NCLS) = o;
        }
    }
}

extern "C" void kernel_launch(void* const* d_in, const int* in_sizes, int n_in,
                              void* d_out, int out_size, void* d_ws, size_t ws_size,
                              hipStream_t stream) {
    const float* x    = (const float*)d_in[0];
    const float* W_ih = (const float*)d_in[1];
    const float* W_hh = (const float*)d_in[2];
    const float* b_ih = (const float*)d_in[3];
    const float* b_hh = (const float*)d_in[4];
    const float* W_fc = (const float*)d_in[5];
    const float* b_fc = (const float*)d_in[6];
    float* out = (float*)d_out;

    lstm_2row<<<BB / 2, 64, 0, stream>>>(x, W_ih, W_hh, b_ih, b_hh, W_fc, b_fc, out);
}

// Round 4
// 850.830 us; speedup vs baseline: 1.1831x; 1.1831x over previous
//
#include <hip/hip_runtime.h>

// Problem constants
#define BB   512
#define CC   22
#define TT   1000
#define HH   64
#define NCLS 4
#define RPB  16              // batch rows (MFMA cols) per block
#define NBLK (BB / RPB)      // 32 blocks
#define TC   50              // time steps staged per chunk
#define NCHUNK (TT / TC)
#define FCW  (TT * HH)       // 64000: W_fc row length

typedef _Float16 f16;
typedef __attribute__((ext_vector_type(2))) _Float16 h2;
typedef __attribute__((ext_vector_type(8))) _Float16 f16x8;
typedef __attribute__((ext_vector_type(4))) float    f32x4;

union U16x8 { uint4 q; f16x8 h; f16 e[8]; };

__device__ __forceinline__ float sigm(float x) {
    float e = __expf(-x);
    return __builtin_amdgcn_rcpf(1.0f + e);
}
__device__ __forceinline__ float tanh_(float x) {
    float e = __expf(-2.0f * fabsf(x));   // (0,1], no overflow
    float r = (1.0f - e) * __builtin_amdgcn_rcpf(1.0f + e);
    return copysignf(r, x);
}
__device__ __forceinline__ unsigned pack2(float a, float b) {
    union { unsigned u; h2 h; } c;
    c.h = h2{(f16)a, (f16)b};
    return c.u;
}

// R8: MFMA batched formulation.
// R4/R7 post-mortem: per-SIMD VALU busy ~75-78% (VALUBusy / SIMD-coverage) ->
// the fdot2 design is ISSUE-bound at ~344 dot-cycles per row per step, and 512
// rows can never cover 1024 SIMDs. Fix the algorithm, not the schedule:
//   gates(256x16) = [W_hh | W_ih | 0](256x96) @ [h; x; 0](96x16)
// per block of 16 batch rows, as 12x mfma_f32_16x16x32_f16 per wave per step
// (4 row-tiles x 3 K-tiles), ~60 issue-cyc for 16 rows vs 344/row before.
//
// Layout facts used (guide §3): D: n=lane&15, m=4*(lane>>4)+reg  [HW-verified]
//                               A: m=lane&15, k=8*(lane>>4)+e    [standard CDNA]
//                               B: n=lane&15, k=8*(lane>>4)+e    [standard CDNA]
// Wave w owns row-tiles {w,w+4,w+8,w+12} = gates i,f,g,o of hids 16w..16w+15
// -> c/h update is lane-local (lane: col=lane&15, hids 16w+4q+r, q=lane>>4).
// h exchange: LDS buffer stored B-fragment-LINEAR (slot l <-> lane l's 16 B),
// so reads are 2 conflict-free linear ds_read_b128; writes are 1 ds_write_b64
// per lane (4 contiguous f16: k&7 = 4(q&1)+r). Double-buffered, 1 barrier/step.
// x: pre-staged per chunk in the same fragment-linear layout (K-tile 2 =
// channels 0..21, rows 22..31 zero).
__global__ __launch_bounds__(256, 1) void lstm_mfma(
    const float* __restrict__ x,     // [B, C, T]
    const float* __restrict__ W_ih,  // [4H, C]
    const float* __restrict__ W_hh,  // [4H, H]
    const float* __restrict__ b_ih,  // [4H]
    const float* __restrict__ b_hh,  // [4H]
    const float* __restrict__ W_fc,  // [NCLS, T*H]
    const float* __restrict__ b_fc,  // [NCLS]
    float* __restrict__ out)         // [B, NCLS]
{
    __shared__ uint4 xs[TC * 64];          // 51200 B: x B-fragments, frag-linear
    __shared__ uint4 hb[2 * 128];          // 4096 B: h B-fragments, 2 bufs x 2 K-tiles
    __shared__ float fcp[4][RPB][NCLS];    // 1 KB: FC partial exchange

    const int tid   = threadIdx.x;
    const int w     = tid >> 6;      // wave: owns hids 16w..16w+15
    const int l     = tid & 63;
    const int c     = l & 15;        // batch col within block
    const int q     = l >> 4;
    const int hid0  = 16 * w + 4 * q;  // this lane's first hid
    const int rbase = blockIdx.x * RPB;

    // ---- one-time: A-fragments of W2 = [W_hh | W_ih | 0] + bias C-init ----
    f16x8 wA[4][3];                  // 4 gate-tiles x 3 K-tiles: 48 VGPR
    f32x4 biasf[4];
    #pragma unroll
    for (int g = 0; g < 4; ++g) {
        const int row = 64 * g + 16 * w + c;   // A row: m = lane&15
        const float* whr = W_hh + row * HH;
        const float* wir = W_ih + row * CC;
        #pragma unroll
        for (int kt = 0; kt < 3; ++kt) {
            U16x8 u;
            #pragma unroll
            for (int e = 0; e < 8; ++e) {
                const int k = 32 * kt + 8 * q + e;
                float v = 0.0f;
                if (k < HH) v = whr[k];
                else if (k < HH + CC) v = wir[k - HH];
                u.e[e] = (f16)v;
            }
            wA[g][kt] = u.h;
        }
        const float4 bi = *(const float4*)(b_ih + 64 * g + hid0);
        const float4 bh = *(const float4*)(b_hh + 64 * g + hid0);
        biasf[g][0] = bi.x + bh.x; biasf[g][1] = bi.y + bh.y;
        biasf[g][2] = bi.z + bh.z; biasf[g][3] = bi.w + bh.w;
    }
    #pragma unroll
    for (int g = 0; g < 4; ++g)
        #pragma unroll
        for (int kt = 0; kt < 3; ++kt)
            asm volatile("" : "+v"(wA[g][kt]));   // keep resident, no remat

    // h_0 = 0: zero both h buffers (256 slots, one per thread)
    hb[tid] = uint4{0u, 0u, 0u, 0u};

    float cst[4] = {0.f, 0.f, 0.f, 0.f};   // c for hids hid0..hid0+3, col c
    float fca[4] = {0.f, 0.f, 0.f, 0.f};   // FC partials, 4 classes

    // writer byte offset into an h buffer (constant per thread):
    //   tile = w>>1 (hids 0..31 / 32..63), k = 16(w&1)+4q+r
    //   byte = tile*1024 + ((k>>3)*16 + c)*16 + (k&7)*2, contiguous in r
    const int woff = (w >> 1) * 1024 + (2 * (w & 1) + (q >> 1)) * 256
                   + c * 16 + (q & 1) * 8;

    for (int chunk = 0; chunk < NCHUNK; ++chunk) {
        const int T0 = chunk * TC;
        // ---- stage x chunk as B-fragments (frag-linear, zero-padded) ----
        for (int s = tid; s < TC * 64; s += 256) {
            const int t  = s >> 6, sl = s & 63;
            const int sc = sl & 15, sq = sl >> 4;
            U16x8 u;
            if (sq == 3) {
                u.q = uint4{0u, 0u, 0u, 0u};           // k rows 88..95 = pad
            } else {
                const float* gx = x + (size_t)(rbase + sc) * (CC * TT) + T0 + t;
                #pragma unroll
                for (int e = 0; e < 8; ++e) {
                    const int ch = 8 * sq + e;
                    u.e[e] = (f16)(ch < CC ? gx[ch * TT] : 0.0f);
                }
            }
            xs[s] = u.q;
        }
        __syncthreads();   // publish xs (also orders hb init / prev chunk)

        for (int tt = 0; tt < TC; ++tt) {
            const int tg = T0 + tt;

            // W_fc rows for this step (addresses independent of LDS data ->
            // issue immediately, latency hides under MFMA+activations)
            const float* wp = W_fc + tg * HH + hid0;
            const float4 wf0 = *(const float4*)(wp);
            const float4 wf1 = *(const float4*)(wp + FCW);
            const float4 wf2 = *(const float4*)(wp + 2 * FCW);
            const float4 wf3 = *(const float4*)(wp + 3 * FCW);

            // B-fragments: h (2 K-tiles) + x (1 K-tile), all linear reads
            U16x8 hx0, hx1, xb;
            const int rb = (tt & 1) * 128;
            hx0.q = hb[rb + l];
            hx1.q = hb[rb + 64 + l];
            xb.q  = xs[tt * 64 + l];

            // 12 MFMA: gates for 16 rows, bias as C-init
            f32x4 d0 = __builtin_amdgcn_mfma_f32_16x16x32_f16(wA[0][0], hx0.h, biasf[0], 0, 0, 0);
            f32x4 d1 = __builtin_amdgcn_mfma_f32_16x16x32_f16(wA[1][0], hx0.h, biasf[1], 0, 0, 0);
            f32x4 d2 = __builtin_amdgcn_mfma_f32_16x16x32_f16(wA[2][0], hx0.h, biasf[2], 0, 0, 0);
            f32x4 d3 = __builtin_amdgcn_mfma_f32_16x16x32_f16(wA[3][0], hx0.h, biasf[3], 0, 0, 0);
            d0 = __builtin_amdgcn_mfma_f32_16x16x32_f16(wA[0][1], hx1.h, d0, 0, 0, 0);
            d1 = __builtin_amdgcn_mfma_f32_16x16x32_f16(wA[1][1], hx1.h, d1, 0, 0, 0);
            d2 = __builtin_amdgcn_mfma_f32_16x16x32_f16(wA[2][1], hx1.h, d2, 0, 0, 0);
            d3 = __builtin_amdgcn_mfma_f32_16x16x32_f16(wA[3][1], hx1.h, d3, 0, 0, 0);
            d0 = __builtin_amdgcn_mfma_f32_16x16x32_f16(wA[0][2], xb.h, d0, 0, 0, 0);
            d1 = __builtin_amdgcn_mfma_f32_16x16x32_f16(wA[1][2], xb.h, d1, 0, 0, 0);
            d2 = __builtin_amdgcn_mfma_f32_16x16x32_f16(wA[2][2], xb.h, d2, 0, 0, 0);
            d3 = __builtin_amdgcn_mfma_f32_16x16x32_f16(wA[3][2], xb.h, d3, 0, 0, 0);

            // lane-local LSTM update: 4 hids x 1 col per lane
            float h[4];
            #pragma unroll
            for (int r = 0; r < 4; ++r) {
                const float iv = sigm(d0[r]);
                const float fv = sigm(d1[r]);
                const float gv = tanh_(d2[r]);
                const float ov = sigm(d3[r]);
                cst[r] = fv * cst[r] + iv * gv;
                h[r] = ov * tanh_(cst[r]);
            }

            // fused FC: logits[c][cls] += sum_r h[r] * W_fc[cls][tg*64+hid0+r]
            fca[0] += h[0] * wf0.x + h[1] * wf0.y + h[2] * wf0.z + h[3] * wf0.w;
            fca[1] += h[0] * wf1.x + h[1] * wf1.y + h[2] * wf1.z + h[3] * wf1.w;
            fca[2] += h[0] * wf2.x + h[1] * wf2.y + h[2] * wf2.z + h[3] * wf2.w;
            fca[3] += h[0] * wf3.x + h[1] * wf3.y + h[2] * wf3.z + h[3] * wf3.w;

            // publish h for t+1 (other buffer), one ds_write_b64 per lane
            uint2 hp;
            hp.x = pack2(h[0], h[1]);
            hp.y = pack2(h[2], h[3]);
            *(uint2*)((char*)hb + ((tt + 1) & 1) * 2048 + woff) = hp;
            __syncthreads();
        }
    }

    // ---- FC reduce: over q-groups (shuffle), then over waves (LDS) ----
    #pragma unroll
    for (int k = 0; k < 4; ++k) {
        fca[k] += __shfl_xor(fca[k], 16);
        fca[k] += __shfl_xor(fca[k], 32);
    }
    if (q == 0) {
        #pragma unroll
        for (int k = 0; k < 4; ++k) fcp[w][c][k] = fca[k];
    }
    __syncthreads();
    if (w == 0 && l < 16) {
        float lg[4];
        #pragma unroll
        for (int k = 0; k < 4; ++k)
            lg[k] = fcp[0][l][k] + fcp[1][l][k] + fcp[2][l][k] + fcp[3][l][k]
                  + b_fc[k];
        const float m  = fmaxf(fmaxf(lg[0], lg[1]), fmaxf(lg[2], lg[3]));
        const float e0 = __expf(lg[0] - m), e1 = __expf(lg[1] - m);
        const float e2 = __expf(lg[2] - m), e3 = __expf(lg[3] - m);
        const float is = __builtin_amdgcn_rcpf(e0 + e1 + e2 + e3);
        float4 o; o.x = e0 * is; o.y = e1 * is; o.z = e2 * is; o.w = e3 * is;
        *(float4*)(out + (rbase + l) * NCLS) = o;
    }
}

extern "C" void kernel_launch(void* const* d_in, const int* in_sizes, int n_in,
                              void* d_out, int out_size, void* d_ws, size_t ws_size,
                              hipStream_t stream) {
    const float* x    = (const float*)d_in[0];
    const float* W_ih = (const float*)d_in[1];
    const float* W_hh = (const float*)d_in[2];
    const float* b_ih = (const float*)d_in[3];
    const float* b_hh = (const float*)d_in[4];
    const float* W_fc = (const float*)d_in[5];
    const float* b_fc = (const float*)d_in[6];
    float* out = (float*)d_out;

    lstm_mfma<<<NBLK, 256, 0, stream>>>(x, W_ih, W_hh, b_ih, b_hh, W_fc, b_fc, out);
}